// Round 1
// baseline (35217.279 us; speedup 1.0000x reference)
//
#include <hip/hip_runtime.h>
#include <hip/hip_bf16.h>

// LSTM forward, T=512 B=128 D=1024 H=1024, fp32 in/out, bf16 MFMA compute.
//
// Design (round 1):
//  - single persistent cooperative kernel, 256 blocks x 256 threads (1 block/CU)
//  - block owns 8 h-cols (=32 gate rows) x 64 batch rows; per-XCD j-partition
//    (bid&7 -> XCD) so each XCD's working set stays in its private L2
//  - W (w_ih ++ w_hh, K=2048) converted to bf16 ONCE into 128 KiB LDS, reused
//    for all 512 steps -> no per-step weight traffic
//  - h state ping-pongs in ws as bf16; c state lives in registers (2/lane)
//  - one grid barrier per step: monotonic agent-scope atomic counter, with
//    __threadfence() (wbl2+inv) for cross-XCD L2 visibility of h
//  - cell gate gather via padded LDS scratch (MFMA C-layout is column-spread)

#define NT 512
#define NB 128
#define ND 1024
#define NH 1024

typedef __attribute__((ext_vector_type(8))) __bf16 bf16x8;
typedef __attribute__((ext_vector_type(4))) float  f32x4;

__device__ __forceinline__ float sigm(float x) { return 1.0f / (1.0f + __expf(-x)); }
__device__ __forceinline__ float tanh_(float x) {
    x = fminf(15.0f, fmaxf(-15.0f, x));
    float e = __expf(-2.0f * x);
    return (1.0f - e) / (1.0f + e);
}

__global__ void __launch_bounds__(256, 1)
lstm_main(const float* __restrict__ x, const float* __restrict__ w_ih,
          const float* __restrict__ b_ih, const float* __restrict__ w_hh,
          const float* __restrict__ b_hh, float* __restrict__ out,
          unsigned short* __restrict__ h_bf, unsigned* __restrict__ bar)
{
    __shared__ uint4 ldsB[8192];       // [k8 0..255][c 0..31], 16B chunks = 128 KiB
    __shared__ float scr[4][16][33];   // per-wave gate scratch, +1 pad vs bank conflicts

    const int tid  = threadIdx.x;
    const int lane = tid & 63;
    const int wid  = tid >> 6;
    const int bid  = blockIdx.x;

    // bid&7 -> XCD (HW round-robins consecutive blockIdx across XCDs)
    const int xcd    = bid & 7;
    const int within = bid >> 3;            // 0..31
    const int mbase  = (within & 1) * 64;   // batch-row half
    const int jbase  = xcd * 128 + (within >> 1) * 8;  // 8 h-cols per block

    // ---- one-time: W rows for this block's 8 h-cols x 4 gates -> bf16 -> LDS ----
    // c = gate*8 + jj ; k8<128: w_ih chunk, k8>=128: w_hh chunk
    for (int idx = tid; idx < 8192; idx += 256) {
        const int c  = idx >> 8;
        const int k8 = idx & 255;
        const int grow = (c >> 3) * NH + jbase + (c & 7);
        const float* src = (k8 < 128) ? (w_ih + (size_t)grow * ND + k8 * 8)
                                      : (w_hh + (size_t)grow * NH + (k8 - 128) * 8);
        const float4 f0 = *(const float4*)src;
        const float4 f1 = *(const float4*)(src + 4);
        bf16x8 v;
        v[0] = (__bf16)f0.x; v[1] = (__bf16)f0.y; v[2] = (__bf16)f0.z; v[3] = (__bf16)f0.w;
        v[4] = (__bf16)f1.x; v[5] = (__bf16)f1.y; v[6] = (__bf16)f1.z; v[7] = (__bf16)f1.w;
        ldsB[k8 * 32 + c] = __builtin_bit_cast(uint4, v);
    }
    __syncthreads();

    // per-lane biases (b_ih+b_hh) for its two (row,jj) cells; c state in regs
    float bi[2], bf_[2], bg[2], bo[2], cst[2] = {0.f, 0.f};
    #pragma unroll
    for (int p = 0; p < 2; ++p) {
        const int gj = jbase + ((lane + p * 64) & 7);
        bi[p]  = b_ih[0 * NH + gj] + b_hh[0 * NH + gj];
        bf_[p] = b_ih[1 * NH + gj] + b_hh[1 * NH + gj];
        bg[p]  = b_ih[2 * NH + gj] + b_hh[2 * NH + gj];
        bo[p]  = b_ih[3 * NH + gj] + b_hh[3 * NH + gj];
    }

    const int lrow  = mbase + wid * 16 + (lane & 15);  // A-frag batch row
    const int kslot = lane >> 4;                       // A/B frag k-group
    const int bcol  = lane & 15;                       // B-frag column

    for (int t = 0; t < NT; ++t) {
        const float* xt = x + (size_t)t * NB * ND + (size_t)lrow * ND + kslot * 8;
        const unsigned short* hb = h_bf + (size_t)(t & 1) * NB * NH
                                        + (size_t)lrow * NH + kslot * 8;
        unsigned short* hbn = h_bf + (size_t)((t + 1) & 1) * NB * NH;

        f32x4 acc0 = {0.f, 0.f, 0.f, 0.f};
        f32x4 acc1 = {0.f, 0.f, 0.f, 0.f};

        // x-part: K = 0..1023 (fp32 -> bf16 inline)
        #pragma unroll 4
        for (int kk = 0; kk < 32; ++kk) {
            const float4 f0 = *(const float4*)(xt + kk * 32);
            const float4 f1 = *(const float4*)(xt + kk * 32 + 4);
            bf16x8 a;
            a[0] = (__bf16)f0.x; a[1] = (__bf16)f0.y; a[2] = (__bf16)f0.z; a[3] = (__bf16)f0.w;
            a[4] = (__bf16)f1.x; a[5] = (__bf16)f1.y; a[6] = (__bf16)f1.z; a[7] = (__bf16)f1.w;
            const int k8 = kk * 4 + kslot;
            const bf16x8 b0 = __builtin_bit_cast(bf16x8, ldsB[k8 * 32 + bcol]);
            const bf16x8 b1 = __builtin_bit_cast(bf16x8, ldsB[k8 * 32 + 16 + bcol]);
            acc0 = __builtin_amdgcn_mfma_f32_16x16x32_bf16(a, b0, acc0, 0, 0, 0);
            acc1 = __builtin_amdgcn_mfma_f32_16x16x32_bf16(a, b1, acc1, 0, 0, 0);
        }
        // h-part: K = 1024..2047 (h already bf16)
        #pragma unroll 4
        for (int kk = 0; kk < 32; ++kk) {
            const bf16x8 a = __builtin_bit_cast(bf16x8, *(const uint4*)(hb + kk * 32));
            const int k8 = 128 + kk * 4 + kslot;
            const bf16x8 b0 = __builtin_bit_cast(bf16x8, ldsB[k8 * 32 + bcol]);
            const bf16x8 b1 = __builtin_bit_cast(bf16x8, ldsB[k8 * 32 + 16 + bcol]);
            acc0 = __builtin_amdgcn_mfma_f32_16x16x32_bf16(a, b0, acc0, 0, 0, 0);
            acc1 = __builtin_amdgcn_mfma_f32_16x16x32_bf16(a, b1, acc1, 0, 0, 0);
        }

        // gates -> LDS scratch (C-layout: col=lane&15, row=(lane>>4)*4+r)
        #pragma unroll
        for (int r = 0; r < 4; ++r) {
            scr[wid][kslot * 4 + r][bcol]      = acc0[r];
            scr[wid][kslot * 4 + r][bcol + 16] = acc1[r];
        }
        __syncthreads();

        // each lane finishes 2 cells (row = q>>3, jj = q&7)
        #pragma unroll
        for (int p = 0; p < 2; ++p) {
            const int q   = lane + p * 64;
            const int row = q >> 3;
            const int jj  = q & 7;
            const float iv = sigm (scr[wid][row][jj]      + bi[p]);
            const float fv = sigm (scr[wid][row][8 + jj]  + bf_[p]);
            const float gv = tanh_(scr[wid][row][16 + jj] + bg[p]);
            const float ov = sigm (scr[wid][row][24 + jj] + bo[p]);
            const float cc = fv * cst[p] + iv * gv;
            cst[p] = cc;
            const float hv = ov * tanh_(cc);
            const int gb = mbase + wid * 16 + row;
            const int gj = jbase + jj;
            out[((size_t)t * NB + gb) * NH + gj] = hv;
            hbn[(size_t)gb * NH + gj] = __builtin_bit_cast(unsigned short, (__bf16)hv);
            if (t == NT - 1)
                out[(size_t)NT * NB * NH + (size_t)gb * NH + gj] = hv;  // h_n
        }

        // ---- grid barrier: release h writes, arrive, spin, acquire ----
        __threadfence();          // wbl2: flush h_bf/hs out of this XCD's L2
        __syncthreads();
        if (tid == 0) {
            __hip_atomic_fetch_add(bar, 1u, __ATOMIC_ACQ_REL, __HIP_MEMORY_SCOPE_AGENT);
            const unsigned tgt = (unsigned)(t + 1) * gridDim.x;
            while (__hip_atomic_load(bar, __ATOMIC_ACQUIRE, __HIP_MEMORY_SCOPE_AGENT) < tgt)
                __builtin_amdgcn_s_sleep(2);
        }
        __syncthreads();
        __threadfence();          // inv: drop stale h_bf lines before next read
    }

    // final cell state c_n
    #pragma unroll
    for (int p = 0; p < 2; ++p) {
        const int q  = lane + p * 64;
        const int gb = mbase + wid * 16 + (q >> 3);
        const int gj = jbase + (q & 7);
        out[(size_t)NT * NB * NH + (size_t)NB * NH + (size_t)gb * NH + gj] = cst[p];
    }
}

extern "C" void kernel_launch(void* const* d_in, const int* in_sizes, int n_in,
                              void* d_out, int out_size, void* d_ws, size_t ws_size,
                              hipStream_t stream)
{
    const float* x    = (const float*)d_in[0];
    const float* w_ih = (const float*)d_in[1];
    const float* b_ih = (const float*)d_in[2];
    const float* w_hh = (const float*)d_in[3];
    const float* b_hh = (const float*)d_in[4];
    float* out = (float*)d_out;

    const size_t hbf_bytes = (size_t)2 * NB * NH * sizeof(unsigned short); // 512 KiB
    if (ws_size < hbf_bytes + 64) return;  // need ping-pong h + barrier counter

    unsigned short* h_bf = (unsigned short*)d_ws;
    unsigned* bar = (unsigned*)((char*)d_ws + hbf_bytes);

    // zero h0 (t=0 reads buffer 0) and the barrier counter, every call
    hipMemsetAsync(d_ws, 0, hbf_bytes + 64, stream);

    void* args[] = { (void*)&x, (void*)&w_ih, (void*)&b_ih, (void*)&w_hh,
                     (void*)&b_hh, (void*)&out, (void*)&h_bf, (void*)&bar };
    hipError_t err = hipLaunchCooperativeKernel((const void*)lstm_main,
                                                dim3(256), dim3(256),
                                                args, 0, stream);
    if (err != hipSuccess) {
        // 256 blocks x 1 block/CU are co-resident on 256 CUs; plain launch
        // keeps the barrier valid if cooperative capture is unsupported.
        lstm_main<<<dim3(256), dim3(256), 0, stream>>>(x, w_ih, b_ih, w_hh,
                                                       b_hh, out, h_bf, bar);
    }
}

// Round 2
// 7931.963 us; speedup vs baseline: 4.4399x; 4.4399x over previous
//
#include <hip/hip_runtime.h>
#include <hip/hip_bf16.h>

// LSTM forward, T=512 B=128 D=1024 H=1024, fp32 in/out, bf16 MFMA compute.
//
// Round 2: kill all L2-wide cache maintenance in the step loop.
//  - h ping-pongs through ws as bf16 via RELAXED agent-scope atomics
//    (global_load/store sc1 -> straight to L3 coherent point). No
//    __threadfence / buffer_wbl2 / buffer_inv anywhere in the loop.
//  - grid barrier: relaxed monotonic counter; __syncthreads() before the
//    arrive-add drains vmcnt(0) so the sc1 h-stores are at L3 first.
//  - x-part GEMM of step t+1 issues between arrive and poll -> overlaps
//    the barrier spin.
//  - 4 independent MFMA accumulator chains; intra-wave gate exchange via
//    per-wave LDS scratch (no block barrier needed).

#define NT 512
#define NB 128
#define ND 1024
#define NH 1024

typedef __attribute__((ext_vector_type(8))) __bf16 bf16x8;
typedef __attribute__((ext_vector_type(4))) float  f32x4;
typedef __attribute__((ext_vector_type(2))) unsigned long long ullx2;

__device__ __forceinline__ float sigm(float x) { return 1.0f / (1.0f + __expf(-x)); }
__device__ __forceinline__ float tanh_(float x) {
    x = fminf(15.0f, fmaxf(-15.0f, x));
    float e = __expf(-2.0f * x);
    return (1.0f - e) / (1.0f + e);
}

__global__ void __launch_bounds__(256, 1)
lstm_main(const float* __restrict__ x, const float* __restrict__ w_ih,
          const float* __restrict__ b_ih, const float* __restrict__ w_hh,
          const float* __restrict__ b_hh, float* __restrict__ out,
          unsigned short* __restrict__ h_bf, unsigned* __restrict__ bar)
{
    __shared__ uint4 ldsB[8192];       // [k8 0..255][c 0..31] bf16x8 chunks = 128 KiB
    __shared__ float scr[4][16][33];   // per-wave gate scratch (intra-wave exchange)

    const int tid  = threadIdx.x;
    const int lane = tid & 63;
    const int wid  = tid >> 6;
    const int bid  = blockIdx.x;

    const int xcd    = bid & 7;                 // consecutive blocks round-robin XCDs
    const int within = bid >> 3;                // 0..31
    const int mbase  = (within & 1) * 64;       // batch-row half
    const int jbase  = xcd * 128 + (within >> 1) * 8;  // 8 h-cols per block

    // ---- one-time: W rows for this block's 8 h-cols x 4 gates -> bf16 -> LDS ----
    for (int idx = tid; idx < 8192; idx += 256) {
        const int c  = idx >> 8;
        const int k8 = idx & 255;
        const int grow = (c >> 3) * NH + jbase + (c & 7);
        const float* src = (k8 < 128) ? (w_ih + (size_t)grow * ND + k8 * 8)
                                      : (w_hh + (size_t)grow * NH + (k8 - 128) * 8);
        const float4 f0 = *(const float4*)src;
        const float4 f1 = *(const float4*)(src + 4);
        bf16x8 v;
        v[0] = (__bf16)f0.x; v[1] = (__bf16)f0.y; v[2] = (__bf16)f0.z; v[3] = (__bf16)f0.w;
        v[4] = (__bf16)f1.x; v[5] = (__bf16)f1.y; v[6] = (__bf16)f1.z; v[7] = (__bf16)f1.w;
        ldsB[k8 * 32 + c] = __builtin_bit_cast(uint4, v);
    }

    // cell assignment: lane owns (crow = lane>>2, jj2=(lane&3)*2) and jj2+1
    const int crow = lane >> 2;
    const int jj2  = (lane & 3) * 2;
    const int gb   = mbase + wid * 16 + crow;   // this lane's batch row
    const int gj   = jbase + jj2;               // this lane's first h-col

    float bias[4][2];
    #pragma unroll
    for (int g = 0; g < 4; ++g)
        #pragma unroll
        for (int u = 0; u < 2; ++u)
            bias[g][u] = b_ih[g * NH + gj + u] + b_hh[g * NH + gj + u];
    float cst[2] = {0.f, 0.f};

    const int lrow  = mbase + wid * 16 + (lane & 15);  // A-frag batch row
    const int kslot = lane >> 4;                       // frag k-group
    const int bcol  = lane & 15;                       // B-frag column

    __syncthreads();   // weights staged

    f32x4 a0a = {0.f,0.f,0.f,0.f}, a0b = {0.f,0.f,0.f,0.f};
    f32x4 a1a = {0.f,0.f,0.f,0.f}, a1b = {0.f,0.f,0.f,0.f};

    // x-part GEMM for step tt (K=0..1023), 4 independent chains
    #define XPART(tt) do {                                                          \
        const float* xt = x + (size_t)(tt) * NB * ND + (size_t)lrow * ND + kslot*8; \
        _Pragma("unroll")                                                           \
        for (int kk = 0; kk < 32; ++kk) {                                           \
            const float4 f0 = *(const float4*)(xt + kk * 32);                       \
            const float4 f1 = *(const float4*)(xt + kk * 32 + 4);                   \
            bf16x8 a;                                                               \
            a[0]=(__bf16)f0.x; a[1]=(__bf16)f0.y; a[2]=(__bf16)f0.z; a[3]=(__bf16)f0.w; \
            a[4]=(__bf16)f1.x; a[5]=(__bf16)f1.y; a[6]=(__bf16)f1.z; a[7]=(__bf16)f1.w; \
            const int k8 = kk * 4 + kslot;                                          \
            const bf16x8 b0 = __builtin_bit_cast(bf16x8, ldsB[k8 * 32 + bcol]);     \
            const bf16x8 b1 = __builtin_bit_cast(bf16x8, ldsB[k8 * 32 + 16 + bcol]);\
            if (kk & 1) {                                                           \
                a0b = __builtin_amdgcn_mfma_f32_16x16x32_bf16(a, b0, a0b, 0,0,0);   \
                a1b = __builtin_amdgcn_mfma_f32_16x16x32_bf16(a, b1, a1b, 0,0,0);   \
            } else {                                                                \
                a0a = __builtin_amdgcn_mfma_f32_16x16x32_bf16(a, b0, a0a, 0,0,0);   \
                a1a = __builtin_amdgcn_mfma_f32_16x16x32_bf16(a, b1, a1a, 0,0,0);   \
            }                                                                       \
        }                                                                           \
    } while (0)

    XPART(0);

    for (int t = 0; t < NT; ++t) {
        // ---- wait for h_{t-1} (all blocks arrived step t-1) ----
        if (t && tid == 0) {
            const unsigned tgt = (unsigned)t * (unsigned)gridDim.x;
            while (__hip_atomic_load(bar, __ATOMIC_RELAXED, __HIP_MEMORY_SCOPE_AGENT) < tgt)
                __builtin_amdgcn_s_sleep(1);
        }
        __syncthreads();

        // ---- h-part GEMM: K=1024..2047, h_{t-1} via sc1 (L2-bypass) loads ----
        {
            const unsigned short* hb = h_bf + (size_t)(t & 1) * NB * NH
                                            + (size_t)lrow * NH + kslot * 8;
            #pragma unroll
            for (int kk = 0; kk < 32; ++kk) {
                ullx2 v;
                v[0] = __hip_atomic_load((const unsigned long long*)(const void*)(hb + kk * 32),
                                         __ATOMIC_RELAXED, __HIP_MEMORY_SCOPE_AGENT);
                v[1] = __hip_atomic_load((const unsigned long long*)(const void*)(hb + kk * 32 + 4),
                                         __ATOMIC_RELAXED, __HIP_MEMORY_SCOPE_AGENT);
                const bf16x8 a = __builtin_bit_cast(bf16x8, v);
                const int k8 = 128 + kk * 4 + kslot;
                const bf16x8 b0 = __builtin_bit_cast(bf16x8, ldsB[k8 * 32 + bcol]);
                const bf16x8 b1 = __builtin_bit_cast(bf16x8, ldsB[k8 * 32 + 16 + bcol]);
                if (kk & 1) {
                    a0b = __builtin_amdgcn_mfma_f32_16x16x32_bf16(a, b0, a0b, 0,0,0);
                    a1b = __builtin_amdgcn_mfma_f32_16x16x32_bf16(a, b1, a1b, 0,0,0);
                } else {
                    a0a = __builtin_amdgcn_mfma_f32_16x16x32_bf16(a, b0, a0a, 0,0,0);
                    a1a = __builtin_amdgcn_mfma_f32_16x16x32_bf16(a, b1, a1a, 0,0,0);
                }
            }
        }

        // ---- intra-wave gate exchange (C-layout: col=lane&15, row=(lane>>4)*4+r) ----
        {
            const f32x4 s0 = a0a + a0b;
            const f32x4 s1 = a1a + a1b;
            #pragma unroll
            for (int r = 0; r < 4; ++r) {
                scr[wid][kslot * 4 + r][bcol]      = s0[r];
                scr[wid][kslot * 4 + r][bcol + 16] = s1[r];
            }
        }
        // same wave wrote all 32 cols of its 16 rows; LDS ops are in-order per wave

        // ---- cell update: lane finishes cells (crow, jj2) and (crow, jj2+1) ----
        float hv[2];
        #pragma unroll
        for (int u = 0; u < 2; ++u) {
            const float iv = sigm (scr[wid][crow][ 0 + jj2 + u] + bias[0][u]);
            const float fv = sigm (scr[wid][crow][ 8 + jj2 + u] + bias[1][u]);
            const float gv = tanh_(scr[wid][crow][16 + jj2 + u] + bias[2][u]);
            const float ov = sigm (scr[wid][crow][24 + jj2 + u] + bias[3][u]);
            const float cc = fv * cst[u] + iv * gv;
            cst[u] = cc;
            hv[u] = ov * tanh_(cc);
        }

        // ---- publish h_t: packed u32, sc1 store straight to L3 ----
        {
            const unsigned short u0 = __builtin_bit_cast(unsigned short, (__bf16)hv[0]);
            const unsigned short u1 = __builtin_bit_cast(unsigned short, (__bf16)hv[1]);
            const unsigned hpack = (unsigned)u0 | ((unsigned)u1 << 16);
            unsigned* dst = (unsigned*)(void*)(h_bf + (size_t)((t + 1) & 1) * NB * NH
                                                    + (size_t)gb * NH + gj);
            __hip_atomic_store(dst, hpack, __ATOMIC_RELAXED, __HIP_MEMORY_SCOPE_AGENT);
        }

        // ---- arrive: syncthreads drains vmcnt(0) => h stores are at L3 ----
        __syncthreads();
        if (tid == 0)
            __hip_atomic_fetch_add(bar, 1u, __ATOMIC_RELAXED, __HIP_MEMORY_SCOPE_AGENT);

        // ---- non-critical stores + next x-part overlap the barrier spin ----
        {
            float2 o; o.x = hv[0]; o.y = hv[1];
            *(float2*)&out[((size_t)t * NB + gb) * NH + gj] = o;
            if (t == NT - 1)
                *(float2*)&out[(size_t)NT * NB * NH + (size_t)gb * NH + gj] = o; // h_n (== hv)
        }
        if (t + 1 < NT) {
            a0a = (f32x4){0.f,0.f,0.f,0.f}; a0b = (f32x4){0.f,0.f,0.f,0.f};
            a1a = (f32x4){0.f,0.f,0.f,0.f}; a1b = (f32x4){0.f,0.f,0.f,0.f};
            XPART(t + 1);
        }
    }

    // final cell state c_n
    {
        float2 cn; cn.x = cst[0]; cn.y = cst[1];
        *(float2*)&out[(size_t)NT * NB * NH + (size_t)NB * NH + (size_t)gb * NH + gj] = cn;
    }
}

extern "C" void kernel_launch(void* const* d_in, const int* in_sizes, int n_in,
                              void* d_out, int out_size, void* d_ws, size_t ws_size,
                              hipStream_t stream)
{
    const float* x    = (const float*)d_in[0];
    const float* w_ih = (const float*)d_in[1];
    const float* b_ih = (const float*)d_in[2];
    const float* w_hh = (const float*)d_in[3];
    const float* b_hh = (const float*)d_in[4];
    float* out = (float*)d_out;

    const size_t hbf_bytes = (size_t)2 * NB * NH * sizeof(unsigned short); // 512 KiB
    if (ws_size < hbf_bytes + 64) return;

    unsigned short* h_bf = (unsigned short*)d_ws;
    unsigned* bar = (unsigned*)((char*)d_ws + hbf_bytes);

    // zero h0 ping-pong buffers and the barrier counter, every call
    hipMemsetAsync(d_ws, 0, hbf_bytes + 64, stream);

    void* args[] = { (void*)&x, (void*)&w_ih, (void*)&b_ih, (void*)&w_hh,
                     (void*)&b_hh, (void*)&out, (void*)&h_bf, (void*)&bar };
    hipError_t err = hipLaunchCooperativeKernel((const void*)lstm_main,
                                                dim3(256), dim3(256),
                                                args, 0, stream);
    if (err != hipSuccess) {
        // 256 blocks x 1 block/CU are co-resident on 256 CUs
        lstm_main<<<dim3(256), dim3(256), 0, stream>>>(x, w_ih, b_ih, w_hh,
                                                       b_hh, out, h_bf, bar);
    }
}